// Round 4
// baseline (154.056 us; speedup 1.0000x reference)
//
#include <hip/hip_runtime.h>

// ImplicitQuadrupleExtractor — B=8, S=512, R=8
// Inputs (f32 unless noted): aspect_logits[B,S,4], opinion_logits[B,S,4],
// rel[B,S,S,R], explicit_aspects[B,S] i32, explicit_opinions[B,S] i32,
// W1[8,32], b1[32], W2[32,16], b2[16], W3[16,1], b3[1]
// Output: a_out[B,S,4] then o_out[B,S,4] concatenated flat (f32, 32768 elems).

#define B 8
#define S 512
#define NROWS (B * S)          // 4096
#define NTH 256                // 4 waves / block, 1 wave per (b,s) row

// d_ws usage: NROWS bytes of flags (bit0=h1bit, bit1=h0bit, bit2=orig-act)

__global__ __launch_bounds__(NTH) void iqe_main(
    const float* __restrict__ aL, const float* __restrict__ oL,
    const float* __restrict__ rel,
    const int* __restrict__ exA, const int* __restrict__ exO,
    const float* __restrict__ W1, const float* __restrict__ b1,
    const float* __restrict__ W2, const float* __restrict__ b2,
    const float* __restrict__ W3, const float* __restrict__ b3,
    float* __restrict__ out, unsigned char* __restrict__ flags)
{
    const int wave = ((blockIdx.x * NTH) + threadIdx.x) >> 6;   // 0..4095
    const int lane = threadIdx.x & 63;
    const int s = wave & (S - 1);
    const int b = wave >> 9;

    // ---- issue the first rel chunk EARLY (decides r4 for ~all rows);
    //      its ~900-cycle HBM latency hides under the compute below. ----
    const float* relrow = rel + (size_t)wave * (S * 8);
    const int jloc = lane >> 3;            // local j within an 8-j chunk
    float relv0 = 0.0f;
    if (s > 0 && jloc < s) relv0 = relrow[lane];   // 256B coalesced (j=0..7, r=0..7)

    // ---- logits as float4 (one 16B load each) ----
    const float4 av4 = ((const float4*)aL)[wave];
    const float4 ov4 = ((const float4*)oL)[wave];
    float x[8] = {av4.x, av4.y, av4.z, av4.w, ov4.x, ov4.y, ov4.z, ov4.w};

    // ---- rules 2/3 window check, lane-parallel (1 load/lane + __any) ----
    const int lo = (s - 3 < 0) ? 0 : s - 3;
    const int hi = (s + 3 > S - 1) ? S - 1 : s + 3;
    const int win = hi - lo + 1;                    // <= 7
    bool myOp = false, myAs = false;
    if (lane < win) {
        const int k = b * S + lo + lane;
        myOp = exO[k] > 0;
        myAs = exA[k] > 0;
    }
    const bool nearOp = __any(myOp);
    const bool nearAs = __any(myAs);

    // ---- rules 2/3: softmax head prob (sum p[:2] > 0.5 <=> e01 > e23);
    //      issued before the MLP so transcendentals overlap the shuffle chain ----
    const float amax = fmaxf(fmaxf(x[0], x[1]), fmaxf(x[2], x[3]));
    const float omax = fmaxf(fmaxf(x[4], x[5]), fmaxf(x[6], x[7]));
    const float ea0 = expf(x[0] - amax), ea1 = expf(x[1] - amax);
    const float ea2 = expf(x[2] - amax), ea3 = expf(x[3] - amax);
    const float eo0 = expf(x[4] - omax), eo1 = expf(x[5] - omax);
    const float eo2 = expf(x[6] - omax), eo3 = expf(x[7] - omax);
    const bool pa = (ea0 + ea1) > (ea2 + ea3);
    const bool po = (eo0 + eo1) > (eo2 + eo3);

    // ---- rule 1: consistency MLP 8->32->16->1, lane-parallel ----
    const int u = lane & 31;
    float h1 = b1[u];
#pragma unroll
    for (int k = 0; k < 8; ++k) h1 = fmaf(x[k], W1[k * 32 + u], h1);
    h1 = fmaxf(h1, 0.0f);

    const int v16 = lane & 15;
    float h2 = b2[v16];
#pragma unroll
    for (int uu = 0; uu < 32; ++uu) {
        float hu = __shfl(h1, uu, 64);              // lanes 0..31 hold h1[0..31]
        h2 = fmaf(hu, W2[uu * 16 + v16], h2);
    }
    h2 = fmaxf(h2, 0.0f);

    float part = h2 * W3[v16];
    part += __shfl_xor(part, 8, 16);
    part += __shfl_xor(part, 4, 16);
    part += __shfl_xor(part, 2, 16);
    part += __shfl_xor(part, 1, 16);
    const float z = part + b3[0];
    const float score = 1.0f / (1.0f + expf(-z));
    const float factor1 = (z < 0.0f) ? 2.0f * score : 1.0f; // score<0.5 <=> z<0
    // (continuous at the boundary: 2*0.5 == 1.0, so an ulp flip is harmless)

    // ---- rule 4: r4 = exists j<s, r: rel[b,s,j,r] > 0.5 (early-exit) ----
    // Lower-triangle hit implies `strength`, so only j<s matters.
    bool r4 = __any(relv0 > 0.5f);
    for (int j0 = 8; j0 < s && !r4; j0 += 8) {      // ~never executes (P=2^-64)
        float v = (j0 + jloc < s) ? relrow[j0 * 8 + lane] : 0.0f;
        r4 = __any(v > 0.5f);
    }

    const bool r2 = pa && !nearOp;
    const bool r3 = po && !nearAs;
    const float fa2 = (r2 ? 0.3f : 1.0f) * (r4 ? 0.7f : 1.0f);
    const float fo2 = (r3 ? 0.3f : 1.0f);

    // ---- base rows (pre-isolation); same FP op order as reference ----
    const float ab0 = (x[0] * factor1) * fa2;
    const float ab1 = (x[1] * factor1) * fa2;
    const float ab2 = x[2] * factor1;
    const float ab3 = x[3] * factor1;
    const float ob0 = (x[4] * factor1) * fo2;
    const float ob1 = (x[5] * factor1) * fo2;
    const float ob2 = x[6] * factor1;
    const float ob3 = x[7] * factor1;

    // ---- activity bits for the isolation scan ----
    const float m1 = fmaxf(fmaxf(fmaxf(ab0, ab1), fmaxf(ab2, ab3)),
                           fmaxf(fmaxf(ob0, ob1), fmaxf(ob2, ob3)));
    const float m0 = fmaxf(fmaxf(fmaxf(ab0 * 0.1f, ab1 * 0.1f), fmaxf(ab2, ab3)),
                           fmaxf(fmaxf(ob0 * 0.1f, ob1 * 0.1f), fmaxf(ob2, ob3)));
    const bool h1bit = m1 > 0.5f;                       // act(final row) if f==1.0
    const bool h0bit = m0 > 0.5f;                       // act(final row) if f==0.1
    const bool orig = (amax > 0.5f) || (omax > 0.5f);   // act of ORIGINAL row

    if (lane == 0) {
        float4* outa = (float4*)out;                    // a section
        float4* outo = (float4*)(out + NROWS * 4);      // o section
        outa[wave] = make_float4(ab0, ab1, ab2, ab3);
        outo[wave] = make_float4(ob0, ob1, ob2, ob3);
        flags[wave] = (unsigned char)((h1bit ? 1 : 0) | (h0bit ? 2 : 0) | (orig ? 4 : 0));
    }
}

__global__ __launch_bounds__(512) void iqe_scan(
    const unsigned char* __restrict__ flags, float* __restrict__ out)
{
    __shared__ unsigned char sflags[NROWS];
    __shared__ unsigned char sf[NROWS];   // 1 -> f=1.0 (no write), 0 -> f=0.1
    const int tid = threadIdx.x;

    for (int i = tid; i < NROWS; i += 512) sflags[i] = flags[i];
    __syncthreads();

    if (tid < B) {
        const unsigned char* fb = sflags + tid * S;
        unsigned char* fo = sf + tid * S;
        bool hp1 = false, hp2 = false;   // h[s-1], h[s-2] (NEG carry -> false)
#pragma unroll 4
        for (int s = 0; s < S; ++s) {
            bool n = false;
            if (s + 1 < S) n |= (fb[s + 1] & 4) != 0;   // original act at s+1
            if (s + 2 < S) n |= (fb[s + 2] & 4) != 0;   // original act at s+2
            const bool activity = hp1 | hp2 | n;
            const unsigned char fl = fb[s];
            const bool h = activity ? ((fl & 1) != 0) : ((fl & 2) != 0);
            fo[s] = activity ? 1 : 0;
            hp2 = hp1; hp1 = h;
        }
    }
    __syncthreads();

    // apply f=0.1 to elements [0:2] of a and o rows; f=1.0 rows untouched
    // (multiply-by-1.0 is exact, so skipping is bit-identical).
    for (int row = tid; row < NROWS; row += 512) {
        if (!sf[row]) {
            float2* pa = (float2*)(out + (size_t)row * 4);
            float2* po = (float2*)(out + (size_t)(NROWS + row) * 4);
            float2 a = *pa, o = *po;
            a.x *= 0.1f; a.y *= 0.1f;
            o.x *= 0.1f; o.y *= 0.1f;
            *pa = a; *po = o;
        }
    }
}

extern "C" void kernel_launch(void* const* d_in, const int* in_sizes, int n_in,
                              void* d_out, int out_size, void* d_ws, size_t ws_size,
                              hipStream_t stream) {
    const float* aL  = (const float*)d_in[0];
    const float* oL  = (const float*)d_in[1];
    const float* rel = (const float*)d_in[2];
    const int*   exA = (const int*)d_in[3];
    const int*   exO = (const int*)d_in[4];
    const float* W1  = (const float*)d_in[5];
    const float* b1  = (const float*)d_in[6];
    const float* W2  = (const float*)d_in[7];
    const float* b2  = (const float*)d_in[8];
    const float* W3  = (const float*)d_in[9];
    const float* b3  = (const float*)d_in[10];

    float* out = (float*)d_out;
    unsigned char* flags = (unsigned char*)d_ws;   // NROWS bytes (4 KB)

    const int nblocks = NROWS / (NTH / 64);        // 1024 blocks, 1 wave per row
    iqe_main<<<nblocks, NTH, 0, stream>>>(aL, oL, rel, exA, exO,
                                          W1, b1, W2, b2, W3, b3, out, flags);
    iqe_scan<<<1, 512, 0, stream>>>(flags, out);
}

// Round 9
// 124.537 us; speedup vs baseline: 1.2370x; 1.2370x over previous
//
#include <hip/hip_runtime.h>

// ImplicitQuadrupleExtractor — B=8, S=512, R=8
// Inputs (f32 unless noted): aspect_logits[B,S,4], opinion_logits[B,S,4],
// rel[B,S,S,R], explicit_aspects[B,S] i32, explicit_opinions[B,S] i32,
// W1[8,32], b1[32], W2[32,16], b2[16], W3[16,1], b3[1]
// Output: a_out[B,S,4] then o_out[B,S,4] concatenated flat (f32, 32768 elems).

#define B 8
#define S 512
#define NROWS (B * S)          // 4096
#define NTH 256                // 4 waves / block, 1 wave per (b,s) row

typedef unsigned long long u64;

// d_ws usage: NROWS bytes of flags (bit0=h1bit, bit1=h0bit, bit2=orig-act)

__global__ __launch_bounds__(NTH) void iqe_main(
    const float* __restrict__ aL, const float* __restrict__ oL,
    const float* __restrict__ rel,
    const int* __restrict__ exA, const int* __restrict__ exO,
    const float* __restrict__ W1, const float* __restrict__ b1,
    const float* __restrict__ W2, const float* __restrict__ b2,
    const float* __restrict__ W3, const float* __restrict__ b3,
    float* __restrict__ out, unsigned char* __restrict__ flags)
{
    const int wave = ((blockIdx.x * NTH) + threadIdx.x) >> 6;   // 0..4095
    const int lane = threadIdx.x & 63;
    const int s = wave & (S - 1);
    const int b = wave >> 9;

    // ---- issue the first rel chunk EARLY (decides r4 for ~all rows);
    //      its ~900-cycle HBM latency hides under the compute below. ----
    const float* relrow = rel + (size_t)wave * (S * 8);
    const int jloc = lane >> 3;            // local j within an 8-j chunk
    float relv0 = 0.0f;
    if (s > 0 && jloc < s) relv0 = relrow[lane];   // 256B coalesced (j=0..7, r=0..7)

    // ---- logits as float4 (one 16B load each) ----
    const float4 av4 = ((const float4*)aL)[wave];
    const float4 ov4 = ((const float4*)oL)[wave];
    float x[8] = {av4.x, av4.y, av4.z, av4.w, ov4.x, ov4.y, ov4.z, ov4.w};

    // ---- rules 2/3 window check, lane-parallel (1 load/lane + __any) ----
    const int lo = (s - 3 < 0) ? 0 : s - 3;
    const int hi = (s + 3 > S - 1) ? S - 1 : s + 3;
    const int win = hi - lo + 1;                    // <= 7
    bool myOp = false, myAs = false;
    if (lane < win) {
        const int k = b * S + lo + lane;
        myOp = exO[k] > 0;
        myAs = exA[k] > 0;
    }
    const bool nearOp = __any(myOp);
    const bool nearAs = __any(myAs);

    // ---- rules 2/3: softmax head prob (sum p[:2] > 0.5 <=> e01 > e23) ----
    const float amax = fmaxf(fmaxf(x[0], x[1]), fmaxf(x[2], x[3]));
    const float omax = fmaxf(fmaxf(x[4], x[5]), fmaxf(x[6], x[7]));
    const float ea0 = expf(x[0] - amax), ea1 = expf(x[1] - amax);
    const float ea2 = expf(x[2] - amax), ea3 = expf(x[3] - amax);
    const float eo0 = expf(x[4] - omax), eo1 = expf(x[5] - omax);
    const float eo2 = expf(x[6] - omax), eo3 = expf(x[7] - omax);
    const bool pa = (ea0 + ea1) > (ea2 + ea3);
    const bool po = (eo0 + eo1) > (eo2 + eo3);

    // ---- rule 1: consistency MLP 8->32->16->1, lane-parallel ----
    const int u = lane & 31;
    float h1 = b1[u];
#pragma unroll
    for (int k = 0; k < 8; ++k) h1 = fmaf(x[k], W1[k * 32 + u], h1);
    h1 = fmaxf(h1, 0.0f);

    const int v16 = lane & 15;
    float h2 = b2[v16];
#pragma unroll
    for (int uu = 0; uu < 32; ++uu) {
        float hu = __shfl(h1, uu, 64);              // lanes 0..31 hold h1[0..31]
        h2 = fmaf(hu, W2[uu * 16 + v16], h2);
    }
    h2 = fmaxf(h2, 0.0f);

    float part = h2 * W3[v16];
    part += __shfl_xor(part, 8, 16);
    part += __shfl_xor(part, 4, 16);
    part += __shfl_xor(part, 2, 16);
    part += __shfl_xor(part, 1, 16);
    const float z = part + b3[0];
    const float score = 1.0f / (1.0f + expf(-z));
    const float factor1 = (z < 0.0f) ? 2.0f * score : 1.0f; // score<0.5 <=> z<0

    // ---- rule 4: r4 = exists j<s, r: rel[b,s,j,r] > 0.5 (early-exit) ----
    // Lower-triangle hit implies `strength`, so only j<s matters.
    bool r4 = __any(relv0 > 0.5f);
    for (int j0 = 8; j0 < s && !r4; j0 += 8) {      // ~never executes (P=2^-64)
        float v = (j0 + jloc < s) ? relrow[j0 * 8 + lane] : 0.0f;
        r4 = __any(v > 0.5f);
    }

    const bool r2 = pa && !nearOp;
    const bool r3 = po && !nearAs;
    const float fa2 = (r2 ? 0.3f : 1.0f) * (r4 ? 0.7f : 1.0f);
    const float fo2 = (r3 ? 0.3f : 1.0f);

    // ---- base rows (pre-isolation); same FP op order as reference ----
    const float ab0 = (x[0] * factor1) * fa2;
    const float ab1 = (x[1] * factor1) * fa2;
    const float ab2 = x[2] * factor1;
    const float ab3 = x[3] * factor1;
    const float ob0 = (x[4] * factor1) * fo2;
    const float ob1 = (x[5] * factor1) * fo2;
    const float ob2 = x[6] * factor1;
    const float ob3 = x[7] * factor1;

    // ---- activity bits for the isolation scan ----
    const float m1 = fmaxf(fmaxf(fmaxf(ab0, ab1), fmaxf(ab2, ab3)),
                           fmaxf(fmaxf(ob0, ob1), fmaxf(ob2, ob3)));
    const float m0 = fmaxf(fmaxf(fmaxf(ab0 * 0.1f, ab1 * 0.1f), fmaxf(ab2, ab3)),
                           fmaxf(fmaxf(ob0 * 0.1f, ob1 * 0.1f), fmaxf(ob2, ob3)));
    const bool h1bit = m1 > 0.5f;                       // act(final row) if f==1.0
    const bool h0bit = m0 > 0.5f;                       // act(final row) if f==0.1
    const bool orig = (amax > 0.5f) || (omax > 0.5f);   // act of ORIGINAL row

    if (lane == 0) {
        float4* outa = (float4*)out;                    // a section
        float4* outo = (float4*)(out + NROWS * 4);      // o section
        outa[wave] = make_float4(ab0, ab1, ab2, ab3);
        outo[wave] = make_float4(ob0, ob1, ob2, ob3);
        flags[wave] = (unsigned char)((h1bit ? 1 : 0) | (h0bit ? 2 : 0) | (orig ? 4 : 0));
    }
}

// pack LSB of each of 8 bytes into 8 bits (exact: product bit 56+i collects
// byte i's LSB only — 8j+7k=49+i has the unique solution j=i,k=7-i)
__device__ __forceinline__ u64 pack8(u64 x) {
    return (x * 0x0102040810204080ULL) >> 56;
}

// 64 threads, 1 wave. Thread t: batch b=t>>3, word w=t&7 (rows b*512+w*64 .. +63).
__global__ __launch_bounds__(64) void iqe_scan2(
    const unsigned char* __restrict__ flags, float* __restrict__ out)
{
    __shared__ u64 sh1[64], sh0[64], snm[64], sact[64];
    const int t = threadIdx.x;
    const int b = t >> 3;
    const int w = t & 7;

    // ---- pack this thread's 64 flag bytes into three 64-bit masks ----
    const u64* fp = (const u64*)(flags + (size_t)b * S + (size_t)w * 64);
    u64 h1m = 0, h0m = 0, orm = 0;
#pragma unroll
    for (int c = 0; c < 8; ++c) {
        const u64 v = fp[c];                           // 8 flag bytes
        h1m |= pack8(v        & 0x0101010101010101ULL) << (8 * c);
        h0m |= pack8((v >> 1) & 0x0101010101010101ULL) << (8 * c);
        orm |= pack8((v >> 2) & 0x0101010101010101ULL) << (8 * c);
    }

    // n[s] = orig[s+1] | orig[s+2]; cross-word bits come from the next word.
    // (w==7: rows beyond S are NEG-padded -> act false -> 0)
    u64 ornext = __shfl(orm, (t + 1) & 63, 64);
    if (w == 7) ornext = 0;
    const u64 nm = (orm >> 1) | (ornext << 63) | (orm >> 2) | (ornext << 62);

    sh1[t] = h1m; sh0[t] = h0m; snm[t] = nm;
    __syncthreads();

    // ---- serial 2-bit-carry recurrence, pure registers, lane b per batch ----
    if (t < B) {
        const int base = t * 8;
        unsigned int hp1 = 0, hp2 = 0;   // h[s-1], h[s-2]; NEG carry -> 0
        for (int ww = 0; ww < 8; ++ww) {
            u64 h1w = sh1[base + ww];
            u64 h0w = sh0[base + ww];
            u64 nw  = snm[base + ww];
            u64 aw  = 0;
            for (int i = 0; i < 64; ++i) {
                const unsigned int act = hp1 | hp2 | (unsigned int)(nw & 1u);
                const unsigned int h =
                    (unsigned int)((act ? h1w : h0w) & 1u);
                aw |= (u64)act << i;
                hp2 = hp1; hp1 = h;
                h1w >>= 1; h0w >>= 1; nw >>= 1;
            }
            sact[base + ww] = aw;
        }
    }
    __syncthreads();

    // ---- fixup: rows with act==0 get f=0.1 on elems [0:2] of a and o.
    //      act==1 rows untouched (×1.0 exact). Inactive rows ~0.2% of 4096.
    const u64 aw = sact[t];
    u64 inact = ~aw;
    const int row0 = b * S + w * 64;
    while (inact) {
        const int i = __builtin_ctzll(inact);
        inact &= inact - 1;
        const int row = row0 + i;
        float2* pa = (float2*)(out + (size_t)row * 4);
        float2* po = (float2*)(out + (size_t)(NROWS + row) * 4);
        float2 a = *pa, o = *po;
        a.x *= 0.1f; a.y *= 0.1f;
        o.x *= 0.1f; o.y *= 0.1f;
        *pa = a; *po = o;
    }
}

extern "C" void kernel_launch(void* const* d_in, const int* in_sizes, int n_in,
                              void* d_out, int out_size, void* d_ws, size_t ws_size,
                              hipStream_t stream) {
    const float* aL  = (const float*)d_in[0];
    const float* oL  = (const float*)d_in[1];
    const float* rel = (const float*)d_in[2];
    const int*   exA = (const int*)d_in[3];
    const int*   exO = (const int*)d_in[4];
    const float* W1  = (const float*)d_in[5];
    const float* b1  = (const float*)d_in[6];
    const float* W2  = (const float*)d_in[7];
    const float* b2  = (const float*)d_in[8];
    const float* W3  = (const float*)d_in[9];
    const float* b3  = (const float*)d_in[10];

    float* out = (float*)d_out;
    unsigned char* flags = (unsigned char*)d_ws;   // NROWS bytes (4 KB)

    const int nblocks = NROWS / (NTH / 64);        // 1024 blocks, 1 wave per row
    iqe_main<<<nblocks, NTH, 0, stream>>>(aL, oL, rel, exA, exO,
                                          W1, b1, W2, b2, W3, b3, out, flags);
    iqe_scan2<<<1, 64, 0, stream>>>(flags, out);
}